// Round 3
// baseline (115.551 us; speedup 1.0000x reference)
//
#include <hip/hip_runtime.h>
#include <hip/hip_bf16.h>
#include <math.h>

// Problem constants (B=4096, D=128, T=0.5 -> 1/T = 2)
#define BB       4096
#define N2       8192          // 2B rows of z
#define DIMS     128
#define WAVES    4
#define ROWTILES 8             // 16-row MFMA tiles per wave
#define ROWS_PER_WAVE   128    // ROWTILES * 16
#define ROWS_PER_BLOCK  512    // WAVES * ROWS_PER_WAVE
#define COL_SPLIT       32
#define COLS_PER_BLOCK  256    // N2 / COL_SPLIT
#define GRID            512    // (N2/ROWS_PER_BLOCK) * COL_SPLIT = 16*32

// z rows pre-scaled by ZSCALE so the MFMA dot yields sim * 2*log2(e),
// i.e. exp(sim/T) = exp2(acc). ZSCALE^2 = 2*log2(e) = 2.8853900818.
#define ZSCALE   1.6986436f
// diagonal term exp(2*|z_r|^2) ~= e^2 — included in denom, subtracted here.
#define DIAG_E2  7.38905609893065f

typedef __attribute__((ext_vector_type(8))) short short8;   // 8 x bf16 (4 VGPRs)
typedef __attribute__((ext_vector_type(4))) float float4v;  // MFMA C/D

// ---------------------------------------------------------------------------
// Kernel 1: normalize rows (fp32), positives (fp32), write z bf16 * ZSCALE.
// Also zeroes denom (blocks 0..31) and the completion counter (block 32).
// One wave per row-pair r: emb_i[r] -> z[r], emb_j[r] -> z[r+B].
// ---------------------------------------------------------------------------
__global__ __launch_bounds__(256) void norm_kernel(
    const float* __restrict__ emb_i, const float* __restrict__ emb_j,
    __hip_bfloat16* __restrict__ z, float* __restrict__ pos,
    float* __restrict__ denom, unsigned int* __restrict__ counter) {
  if (blockIdx.x < N2 / 256) denom[blockIdx.x * 256 + threadIdx.x] = 0.0f;
  if (blockIdx.x == 32 && threadIdx.x == 0) *counter = 0u;

  int gw   = (blockIdx.x * blockDim.x + threadIdx.x) >> 6;  // row pair
  int lane = threadIdx.x & 63;
  if (gw >= BB) return;

  const float2* ei = (const float2*)(emb_i + (size_t)gw * DIMS);
  const float2* ej = (const float2*)(emb_j + (size_t)gw * DIMS);
  float2 a = ei[lane];
  float2 b = ej[lane];

  float sa = a.x * a.x + a.y * a.y;
  float sb = b.x * b.x + b.y * b.y;
  #pragma unroll
  for (int m = 32; m; m >>= 1) {
    sa += __shfl_xor(sa, m, 64);
    sb += __shfl_xor(sb, m, 64);
  }
  float inva = 1.0f / fmaxf(sqrtf(sa), 1e-12f);
  float invb = 1.0f / fmaxf(sqrtf(sb), 1e-12f);

  float zi0 = a.x * inva, zi1 = a.y * inva;
  float zj0 = b.x * invb, zj1 = b.y * invb;

  // positive pair dot in unscaled fp32 (matches reference's fp32 einsum)
  float p = zi0 * zj0 + zi1 * zj1;
  #pragma unroll
  for (int m = 32; m; m >>= 1) p += __shfl_xor(p, m, 64);
  if (lane == 0) pos[gw] = p;

  __hip_bfloat162* zr_i = (__hip_bfloat162*)(z + (size_t)gw * DIMS);
  __hip_bfloat162* zr_j = (__hip_bfloat162*)(z + (size_t)(gw + BB) * DIMS);
  __hip_bfloat162 vi, vj;
  vi.x = __float2bfloat16(zi0 * ZSCALE); vi.y = __float2bfloat16(zi1 * ZSCALE);
  vj.x = __float2bfloat16(zj0 * ZSCALE); vj.y = __float2bfloat16(zj1 * ZSCALE);
  zr_i[lane] = vi;
  zr_j[lane] = vj;
}

// ---------------------------------------------------------------------------
// Kernel 2: fused sim-GEMM + exp2 + row-sum + (last block) finalize.
// Block = 256 threads (4 waves), owns 512 rows x 256 columns.
// The ENTIRE 256-col x 128-k B-panel (64 KB) is staged in LDS once with an
// XOR swizzle (col8 ^ row&15) -> power-of-2 stride with 2-way-max bank
// access (free). One barrier total; then 16 column tiles of pure
// ds_read_b128 -> 32 MFMA -> exp2 streaming. Each wave pins 128 rows of A
// (32 short8 = 128 VGPRs), so each B read feeds 8 MFMAs.
// MFMA 16x16x32 bf16: A[m=lane&15][k=quad*8+j], B[k=quad*8+j][n=lane&15],
// C: col=lane&15, row=quad*4+reg (HW-verified layouts).
// Diagonal included, subtracted in finalize. Last block (device-scope
// counter) computes the loss -> 2 dispatches total.
// ---------------------------------------------------------------------------
__global__ __launch_bounds__(256, 2) void simloss_main(
    const __hip_bfloat16* __restrict__ z, float* __restrict__ denom,
    const float* __restrict__ pos, float* __restrict__ out,
    unsigned int* __restrict__ counter) {
  const int blk     = blockIdx.x;
  const int rowBase = (blk >> 5) * ROWS_PER_BLOCK;   // 0..15 -> *512
  const int colBase = (blk & 31) * COLS_PER_BLOCK;   // 0..31 -> *256
  const int tid  = threadIdx.x;
  const int wave = tid >> 6;
  const int lane = tid & 63;
  const int lr   = lane & 15;          // A-row / B-col / C-col within tile
  const int quad = lane >> 4;          // k-group for A/B, row-group for C

  __shared__ short lds[COLS_PER_BLOCK * DIMS];  // 65536 B exactly

  const ushort* zp = (const ushort*)z;

  // ---- Stage the whole B-panel: 4096 short8, 16 per thread, swizzled. ----
  {
    const short8* src = (const short8*)(zp + (size_t)colBase * DIMS);
    #pragma unroll 4
    for (int i = 0; i < 16; i++) {
      int idx  = tid + 256 * i;          // linear short8 index
      int row  = idx >> 4;               // 16 short8 per 128-short row
      int col8 = idx & 15;
      int sw   = col8 ^ (row & 15);      // XOR swizzle
      *(short8*)&lds[row * DIMS + sw * 8] = src[idx];
    }
  }
  __syncthreads();  // the only barrier before the tail

  // ---- A fragments: 128 rows x 128 k per wave, pinned in VGPRs. ----
  short8 afrag[ROWTILES][4];
  #pragma unroll
  for (int rt = 0; rt < ROWTILES; rt++) {
    const int arow = rowBase + wave * ROWS_PER_WAVE + rt * 16 + lr;
    const short8* ap = (const short8*)(zp + (size_t)arow * DIMS + quad * 8);
    afrag[rt][0] = ap[0];
    afrag[rt][1] = ap[4];   // +32 shorts (k += 32)
    afrag[rt][2] = ap[8];
    afrag[rt][3] = ap[12];
  }

  float rowsum[ROWTILES][4];
  #pragma unroll
  for (int rt = 0; rt < ROWTILES; rt++)
    #pragma unroll
    for (int r = 0; r < 4; r++) rowsum[rt][r] = 0.0f;

  // ---- 16 column tiles of 16; no barriers. ----
  for (int t = 0; t < 16; t++) {
    const int row = t * 16 + lr;                 // B-panel row (= z column)
    short8 bkk[4];
    #pragma unroll
    for (int kk = 0; kk < 4; kk++) {
      int col8 = (kk * 4 + quad) ^ lr;           // swizzled k-group position
      bkk[kk] = *(const short8*)&lds[row * DIMS + col8 * 8];
    }
    #pragma unroll
    for (int rt = 0; rt < ROWTILES; rt++) {
      float4v acc = {0.0f, 0.0f, 0.0f, 0.0f};
      acc = __builtin_amdgcn_mfma_f32_16x16x32_bf16(afrag[rt][0], bkk[0], acc, 0, 0, 0);
      acc = __builtin_amdgcn_mfma_f32_16x16x32_bf16(afrag[rt][1], bkk[1], acc, 0, 0, 0);
      acc = __builtin_amdgcn_mfma_f32_16x16x32_bf16(afrag[rt][2], bkk[2], acc, 0, 0, 0);
      acc = __builtin_amdgcn_mfma_f32_16x16x32_bf16(afrag[rt][3], bkk[3], acc, 0, 0, 0);
      // exp(sim/T) = exp2(acc) thanks to ZSCALE pre-scaling.
      #pragma unroll
      for (int r = 0; r < 4; r++)
        rowsum[rt][r] += __builtin_amdgcn_exp2f(acc[r]);
    }
  }

  // ---- Reduce across the 16 lanes of each quad, then one atomic per row. ----
  #pragma unroll
  for (int m = 1; m < 16; m <<= 1) {
    #pragma unroll
    for (int rt = 0; rt < ROWTILES; rt++)
      #pragma unroll
      for (int r = 0; r < 4; r++)
        rowsum[rt][r] += __shfl_xor(rowsum[rt][r], m, 64);
  }
  if (lr == 0) {
    #pragma unroll
    for (int rt = 0; rt < ROWTILES; rt++)
      #pragma unroll
      for (int r = 0; r < 4; r++)
        atomicAdd(&denom[rowBase + wave * ROWS_PER_WAVE + rt * 16 + quad * 4 + r],
                  rowsum[rt][r]);
  }

  // ---- Last-block finalize: loss = mean(log(denom - e^2) - 2*pos). ----
  __threadfence();          // release: my denom atomics ordered before counter
  __syncthreads();          // all waves' atomics issued (and LDS reads done)
  if (tid == 0) {
    unsigned int old = atomicAdd(counter, 1u);
    *(int*)&lds[0] = (old == GRID - 1) ? 1 : 0;  // reuse LDS (at 64KB cap)
  }
  __syncthreads();
  if (*(int*)&lds[0]) {
    __threadfence();        // acquire side
    double acc = 0.0;
    for (int r = tid; r < N2; r += 256) {
      float d = __hip_atomic_load(&denom[r], __ATOMIC_RELAXED,
                                  __HIP_MEMORY_SCOPE_AGENT);
      acc += (double)(logf(d - DIAG_E2) - 2.0f * pos[r & (BB - 1)]);
    }
    double* sred = (double*)lds;
    sred[tid] = acc;
    __syncthreads();
    for (int s = 128; s; s >>= 1) {
      if (tid < s) sred[tid] += sred[tid + s];
      __syncthreads();
    }
    if (tid == 0) out[0] = (float)(sred[0] / (double)N2);
  }
}

// ---------------------------------------------------------------------------
extern "C" void kernel_launch(void* const* d_in, const int* in_sizes, int n_in,
                              void* d_out, int out_size, void* d_ws, size_t ws_size,
                              hipStream_t stream) {
  const float* emb_i = (const float*)d_in[0];
  const float* emb_j = (const float*)d_in[1];

  // workspace layout
  __hip_bfloat16* z = (__hip_bfloat16*)d_ws;                       // 2 MiB
  float* pos   = (float*)((char*)d_ws + (size_t)N2 * DIMS * 2);    // 4096 f32
  float* denom = (float*)((char*)pos + BB * sizeof(float));        // 8192 f32
  unsigned int* counter = (unsigned int*)((char*)denom + N2 * sizeof(float));

  norm_kernel<<<BB / 4, 256, 0, stream>>>(emb_i, emb_j, z, pos, denom, counter);
  simloss_main<<<GRID, 256, 0, stream>>>(z, denom, pos, (float*)d_out, counter);
}

// Round 4
// 109.253 us; speedup vs baseline: 1.0576x; 1.0576x over previous
//
#include <hip/hip_runtime.h>
#include <hip/hip_bf16.h>
#include <math.h>

// Problem constants (B=4096, D=128, T=0.5 -> 1/T = 2)
#define BB       4096
#define N2       8192          // 2B rows of z
#define DIMS     128
#define WAVES    4
#define ROWTILES 4             // 16-row MFMA tiles per wave
#define ROWS_PER_WAVE   64     // ROWTILES * 16
#define ROWS_PER_BLOCK  256    // WAVES * ROWS_PER_WAVE
#define COLS_PER_BLOCK  128
#define COL_SPLIT       (N2 / COLS_PER_BLOCK)    // 64
#define GRID            ((N2 / ROWS_PER_BLOCK) * COL_SPLIT)  // 32*64 = 2048

// z rows pre-scaled by ZSCALE so the MFMA dot yields sim * 2*log2(e),
// i.e. exp(sim/T) = exp2(acc). ZSCALE^2 = 2*log2(e) = 2.8853900818.
#define ZSCALE   1.6986436f
// diagonal term exp(2*|z_r|^2) ~= e^2 — included in denom, subtracted in finalize.
#define DIAG_E2  7.38905609893065f

typedef __attribute__((ext_vector_type(8))) short short8;   // 8 x bf16 (4 VGPRs)
typedef __attribute__((ext_vector_type(4))) float float4v;  // MFMA C/D

// ---------------------------------------------------------------------------
// Kernel 1: normalize rows (fp32), positives (fp32), write z bf16 * ZSCALE.
// Also zeroes denom (blocks 0..31). One wave per row-pair r.
// ---------------------------------------------------------------------------
__global__ __launch_bounds__(256) void norm_kernel(
    const float* __restrict__ emb_i, const float* __restrict__ emb_j,
    __hip_bfloat16* __restrict__ z, float* __restrict__ pos,
    float* __restrict__ denom) {
  if (blockIdx.x < N2 / 256) denom[blockIdx.x * 256 + threadIdx.x] = 0.0f;

  int gw   = (blockIdx.x * blockDim.x + threadIdx.x) >> 6;  // row pair
  int lane = threadIdx.x & 63;
  if (gw >= BB) return;

  const float2* ei = (const float2*)(emb_i + (size_t)gw * DIMS);
  const float2* ej = (const float2*)(emb_j + (size_t)gw * DIMS);
  float2 a = ei[lane];
  float2 b = ej[lane];

  float sa = a.x * a.x + a.y * a.y;
  float sb = b.x * b.x + b.y * b.y;
  #pragma unroll
  for (int m = 32; m; m >>= 1) {
    sa += __shfl_xor(sa, m, 64);
    sb += __shfl_xor(sb, m, 64);
  }
  float inva = 1.0f / fmaxf(sqrtf(sa), 1e-12f);
  float invb = 1.0f / fmaxf(sqrtf(sb), 1e-12f);

  float zi0 = a.x * inva, zi1 = a.y * inva;
  float zj0 = b.x * invb, zj1 = b.y * invb;

  // positive pair dot in unscaled fp32 (matches reference's fp32 einsum)
  float p = zi0 * zj0 + zi1 * zj1;
  #pragma unroll
  for (int m = 32; m; m >>= 1) p += __shfl_xor(p, m, 64);
  if (lane == 0) pos[gw] = p;

  __hip_bfloat162* zr_i = (__hip_bfloat162*)(z + (size_t)gw * DIMS);
  __hip_bfloat162* zr_j = (__hip_bfloat162*)(z + (size_t)(gw + BB) * DIMS);
  __hip_bfloat162 vi, vj;
  vi.x = __float2bfloat16(zi0 * ZSCALE); vi.y = __float2bfloat16(zi1 * ZSCALE);
  vj.x = __float2bfloat16(zj0 * ZSCALE); vj.y = __float2bfloat16(zj1 * ZSCALE);
  zr_i[lane] = vi;
  zr_j[lane] = vj;
}

// ---------------------------------------------------------------------------
// Kernel 2: fused sim-GEMM + exp2 + row-sum.
// Block = 256 threads (4 waves), owns 256 rows x 128 columns.
// The 128-col x 128-k B-panel (32 KB) is staged in LDS once, XOR-swizzled
// (col8 ^ row&15 -> 2-way-max bank access, free), ONE barrier per block.
// Each wave pins 64 rows of A (16 short8 = 64 VGPRs); each B ds_read_b128
// feeds 4 MFMAs. 4 blocks/CU resident (32KB LDS, <=128 VGPR) so staging of
// one block hides under compute of the other three — no explicit pipelining.
// MFMA 16x16x32 bf16: A[m=lane&15][k=quad*8+j], B[k=quad*8+j][n=lane&15],
// C: col=lane&15, row=quad*4+reg (HW-verified layouts).
// Diagonal included, subtracted in finalize.
// ---------------------------------------------------------------------------
__global__ __launch_bounds__(256, 4) void simloss_main(
    const __hip_bfloat16* __restrict__ z, float* __restrict__ denom) {
  const int blk     = blockIdx.x;
  const int rowBase = (blk >> 6) * ROWS_PER_BLOCK;   // 32 row-blocks
  const int colBase = (blk & 63) * COLS_PER_BLOCK;   // 64 col-blocks
  const int tid  = threadIdx.x;
  const int wave = tid >> 6;
  const int lane = tid & 63;
  const int lr   = lane & 15;          // A-row / B-col / C-col within tile
  const int quad = lane >> 4;          // k-group for A/B, row-group for C

  __shared__ short lds[COLS_PER_BLOCK * DIMS];  // 32768 B

  const ushort* zp = (const ushort*)z;

  // ---- A fragments first (in flight during staging): 64 rows/wave. ----
  short8 afrag[ROWTILES][4];
  #pragma unroll
  for (int rt = 0; rt < ROWTILES; rt++) {
    const int arow = rowBase + wave * ROWS_PER_WAVE + rt * 16 + lr;
    const short8* ap = (const short8*)(zp + (size_t)arow * DIMS + quad * 8);
    afrag[rt][0] = ap[0];
    afrag[rt][1] = ap[4];   // +32 shorts (k += 32)
    afrag[rt][2] = ap[8];
    afrag[rt][3] = ap[12];
  }

  // ---- Stage the B-panel: 2048 short8, 8 per thread, swizzled. ----
  {
    const short8* src = (const short8*)(zp + (size_t)colBase * DIMS);
    #pragma unroll
    for (int i = 0; i < 8; i++) {
      int idx  = tid + 256 * i;          // linear short8 index
      int row  = idx >> 4;               // 16 short8 per 128-short row
      int col8 = idx & 15;
      int sw   = col8 ^ (row & 15);      // XOR swizzle
      *(short8*)&lds[row * DIMS + sw * 8] = src[idx];
    }
  }
  __syncthreads();  // the only barrier

  float rowsum[ROWTILES][4];
  #pragma unroll
  for (int rt = 0; rt < ROWTILES; rt++)
    #pragma unroll
    for (int r = 0; r < 4; r++) rowsum[rt][r] = 0.0f;

  // ---- 8 column tiles of 16; no further barriers. ----
  #pragma unroll
  for (int t = 0; t < 8; t++) {
    const int row = t * 16 + lr;                 // B-panel row (= z column)
    short8 bkk[4];
    #pragma unroll
    for (int kk = 0; kk < 4; kk++) {
      int col8 = (kk * 4 + quad) ^ lr;           // swizzled k-group position
      bkk[kk] = *(const short8*)&lds[row * DIMS + col8 * 8];
    }
    #pragma unroll
    for (int rt = 0; rt < ROWTILES; rt++) {
      float4v acc = {0.0f, 0.0f, 0.0f, 0.0f};
      acc = __builtin_amdgcn_mfma_f32_16x16x32_bf16(afrag[rt][0], bkk[0], acc, 0, 0, 0);
      acc = __builtin_amdgcn_mfma_f32_16x16x32_bf16(afrag[rt][1], bkk[1], acc, 0, 0, 0);
      acc = __builtin_amdgcn_mfma_f32_16x16x32_bf16(afrag[rt][2], bkk[2], acc, 0, 0, 0);
      acc = __builtin_amdgcn_mfma_f32_16x16x32_bf16(afrag[rt][3], bkk[3], acc, 0, 0, 0);
      // exp(sim/T) = exp2(acc) thanks to ZSCALE pre-scaling.
      #pragma unroll
      for (int r = 0; r < 4; r++)
        rowsum[rt][r] += __builtin_amdgcn_exp2f(acc[r]);
    }
  }

  // ---- Reduce across the 16 lanes of each quad, one atomic per row. ----
  #pragma unroll
  for (int m = 1; m < 16; m <<= 1) {
    #pragma unroll
    for (int rt = 0; rt < ROWTILES; rt++)
      #pragma unroll
      for (int r = 0; r < 4; r++)
        rowsum[rt][r] += __shfl_xor(rowsum[rt][r], m, 64);
  }
  if (lr == 0) {
    #pragma unroll
    for (int rt = 0; rt < ROWTILES; rt++)
      #pragma unroll
      for (int r = 0; r < 4; r++)
        atomicAdd(&denom[rowBase + wave * ROWS_PER_WAVE + rt * 16 + quad * 4 + r],
                  rowsum[rt][r]);
  }
}

// ---------------------------------------------------------------------------
// Kernel 3: loss = (1/2B) * sum_r [ log(denom[r] - e^2) - 2*pos[r mod B] ]
// Single block; double accumulation (fp32 naive sum of 8192 ~9-magnitude
// terms would random-walk too close to the threshold).
// ---------------------------------------------------------------------------
__global__ __launch_bounds__(256) void finalize(
    const float* __restrict__ denom, const float* __restrict__ pos,
    float* __restrict__ out) {
  __shared__ double sred[256];
  int tid = threadIdx.x;
  double acc = 0.0;
  for (int r = tid; r < N2; r += 256) {
    acc += (double)(logf(denom[r] - DIAG_E2) - 2.0f * pos[r & (BB - 1)]);
  }
  sred[tid] = acc;
  __syncthreads();
  for (int s = 128; s; s >>= 1) {
    if (tid < s) sred[tid] += sred[tid + s];
    __syncthreads();
  }
  if (tid == 0) out[0] = (float)(sred[0] / (double)N2);
}

// ---------------------------------------------------------------------------
extern "C" void kernel_launch(void* const* d_in, const int* in_sizes, int n_in,
                              void* d_out, int out_size, void* d_ws, size_t ws_size,
                              hipStream_t stream) {
  const float* emb_i = (const float*)d_in[0];
  const float* emb_j = (const float*)d_in[1];

  // workspace layout
  __hip_bfloat16* z = (__hip_bfloat16*)d_ws;                       // 2 MiB
  float* pos   = (float*)((char*)d_ws + (size_t)N2 * DIMS * 2);    // 4096 f32
  float* denom = (float*)((char*)pos + BB * sizeof(float));        // 8192 f32

  norm_kernel<<<BB / 4, 256, 0, stream>>>(emb_i, emb_j, z, pos, denom);
  simloss_main<<<GRID, 256, 0, stream>>>(z, denom);
  finalize<<<1, 256, 0, stream>>>(denom, pos, (float*)d_out);
}